// Round 1
// baseline (21.532 us; speedup 1.0000x reference)
//
#include <hip/hip_runtime.h>

// Quanvolution quantum filter, collapsed analytically:
//   per 2x2 patch (t0,t1,t2,t3), with cq = cos(tq):
//     out[0] = c1*c2*c3
//     out[1] = c0*c1
//     out[2] = c0*c1*c2
//     out[3] = c0*c1*c2*c3
// Derivation: product state Ry rotations -> P(bq=1)=sin^2(tq/2); CNOT ring
// permutes basis states so each Z expectation is E[(-1)^{XOR subset}] =
// prod over subset of (cos^2 - sin^2) = prod cos(tq).

#define BATCH 16384
#define PATCHES 196   // 14 x 14
#define TOTAL (BATCH * PATCHES)

__global__ __launch_bounds__(256) void quanv_kernel(const float* __restrict__ x,
                                                    float* __restrict__ out) {
    int t = blockIdx.x * blockDim.x + threadIdx.x;
    if (t >= TOTAL) return;
    int b = t / PATCHES;
    int p = t - b * PATCHES;
    int r = p / 14;
    int c = p - r * 14;

    const float* img = x + (size_t)b * 784;
    int base = (2 * r) * 28 + 2 * c;

    float2 top = *reinterpret_cast<const float2*>(img + base);        // t0, t1
    float2 bot = *reinterpret_cast<const float2*>(img + base + 28);   // t2, t3

    float c0 = cosf(top.x);
    float c1 = cosf(top.y);
    float c2 = cosf(bot.x);
    float c3 = cosf(bot.y);

    float4 o;
    o.y = c0 * c1;        // meas1
    o.z = o.y * c2;       // meas2
    o.w = o.z * c3;       // meas3
    o.x = c1 * c2 * c3;   // meas0

    *reinterpret_cast<float4*>(out + (size_t)t * 4) = o;
}

extern "C" void kernel_launch(void* const* d_in, const int* in_sizes, int n_in,
                              void* d_out, int out_size, void* d_ws, size_t ws_size,
                              hipStream_t stream) {
    const float* x = (const float*)d_in[0];
    float* out = (float*)d_out;
    int blocks = (TOTAL + 255) / 256;
    quanv_kernel<<<blocks, 256, 0, stream>>>(x, out);
}